// Round 1
// baseline (4951.175 us; speedup 1.0000x reference)
//
#include <hip/hip_runtime.h>

#define T_LEN 512
#define HID 50
#define NBATCH 4096
#define RSTRIDE 52   // row stride for W_hh in LDS: 16B aligned, ~2-way banks (free)

__device__ __forceinline__ float lane_bcast(float v, int l) {
  return __int_as_float(__builtin_amdgcn_readlane(__float_as_int(v), l));
}

__device__ __forceinline__ float fast_sigmoid(float v) {
  return 1.0f / (1.0f + __expf(-v));
}

__global__ __launch_bounds__(256, 4)
void gru_fused_kernel(const float* __restrict__ x,
                      const float* __restrict__ W_ih,
                      const float* __restrict__ W_hh,
                      const float* __restrict__ b_ih,
                      const float* __restrict__ b_hh,
                      const float* __restrict__ W_fc,
                      const float* __restrict__ b_fc,
                      float* __restrict__ out) {
  // W_hh staged once: rows g=0..149 (r:0-49, z:50-99, n:100-149), stride 52, pad zeroed
  __shared__ float sW[150 * RSTRIDE];

  const int tid = threadIdx.x;
  for (int idx = tid; idx < 150 * RSTRIDE; idx += 256) sW[idx] = 0.0f;
  __syncthreads();
  for (int idx = tid; idx < 150 * HID; idx += 256) {
    int g = idx / HID;
    int j = idx - g * HID;
    sW[g * RSTRIDE + j] = W_hh[idx];
  }
  __syncthreads();

  const int lane = tid & 63;
  const int wv   = tid >> 6;
  const int b    = blockIdx.x * 4 + wv;
  const int ic   = (lane < HID) ? lane : (HID - 1);  // lanes 50-63 mirror unit 49 (harmless)

  // per-lane gate constants (W_ih rows ic, 50+ic, 100+ic; fused biases)
  const float u_r0 = W_ih[ic * 3 + 0],        u_r1 = W_ih[ic * 3 + 1],        u_r2 = W_ih[ic * 3 + 2];
  const float u_z0 = W_ih[(50 + ic) * 3 + 0], u_z1 = W_ih[(50 + ic) * 3 + 1], u_z2 = W_ih[(50 + ic) * 3 + 2];
  const float u_n0 = W_ih[(100 + ic) * 3 + 0],u_n1 = W_ih[(100 + ic) * 3 + 1],u_n2 = W_ih[(100 + ic) * 3 + 2];
  const float c_r  = b_ih[ic] + b_hh[ic];
  const float c_z  = b_ih[50 + ic] + b_hh[50 + ic];
  const float c_ni = b_ih[100 + ic];   // outside r*
  const float c_nh = b_hh[100 + ic];   // inside r*

  const float* xb = x + (size_t)b * (T_LEN * 3);

  const float4* Wr4 = (const float4*)(sW + ic * RSTRIDE);
  const float4* Wz4 = (const float4*)(sW + (50 + ic) * RSTRIDE);
  const float4* Wn4 = (const float4*)(sW + (100 + ic) * RSTRIDE);

  float h = 0.0f;

  for (int t = 0; t < T_LEN; ++t) {
    // wave-uniform x loads (scalar); used only after the j-loop so latency hides
    const float x0 = xb[t * 3 + 0];
    const float x1 = xb[t * 3 + 1];
    const float x2 = xb[t * 3 + 2];

    float ar = 0.0f, az = 0.0f, an = 0.0f;
#pragma unroll
    for (int q = 0; q < 13; ++q) {
      const float4 wr = Wr4[q];
      const float4 wz = Wz4[q];
      const float4 wn = Wn4[q];
      const float h0 = lane_bcast(h, 4 * q + 0);
      const float h1 = lane_bcast(h, 4 * q + 1);
      const float h2 = lane_bcast(h, 4 * q + 2);
      const float h3 = lane_bcast(h, 4 * q + 3);
      ar = fmaf(wr.x, h0, ar); ar = fmaf(wr.y, h1, ar); ar = fmaf(wr.z, h2, ar); ar = fmaf(wr.w, h3, ar);
      az = fmaf(wz.x, h0, az); az = fmaf(wz.y, h1, az); az = fmaf(wz.z, h2, az); az = fmaf(wz.w, h3, az);
      an = fmaf(wn.x, h0, an); an = fmaf(wn.y, h1, an); an = fmaf(wn.z, h2, an); an = fmaf(wn.w, h3, an);
    }

    const float gr = fmaf(x0, u_r0, fmaf(x1, u_r1, fmaf(x2, u_r2, c_r)));
    const float gz = fmaf(x0, u_z0, fmaf(x1, u_z1, fmaf(x2, u_z2, c_z)));
    const float gn = fmaf(x0, u_n0, fmaf(x1, u_n1, fmaf(x2, u_n2, c_ni)));

    const float r  = fast_sigmoid(ar + gr);
    const float z  = fast_sigmoid(az + gz);
    const float nv = gn + r * (an + c_nh);
    const float n  = 2.0f / (1.0f + __expf(-2.0f * nv)) - 1.0f;  // tanh

    h = n + z * (h - n);
  }

  // out[b] = b_fc + sum_{i<50} h_i * W_fc[i]
  float p = (lane < HID) ? h * W_fc[lane] : 0.0f;
#pragma unroll
  for (int off = 32; off > 0; off >>= 1) p += __shfl_down(p, off);
  if (lane == 0) out[b] = p + b_fc[0];
}

extern "C" void kernel_launch(void* const* d_in, const int* in_sizes, int n_in,
                              void* d_out, int out_size, void* d_ws, size_t ws_size,
                              hipStream_t stream) {
  const float* x    = (const float*)d_in[0];
  const float* W_ih = (const float*)d_in[1];
  const float* W_hh = (const float*)d_in[2];
  const float* b_ih = (const float*)d_in[3];
  const float* b_hh = (const float*)d_in[4];
  const float* W_fc = (const float*)d_in[5];
  const float* b_fc = (const float*)d_in[6];
  float* out = (float*)d_out;

  dim3 grid(NBATCH / 4);
  dim3 block(256);
  gru_fused_kernel<<<grid, block, 0, stream>>>(x, W_ih, W_hh, b_ih, b_hh, W_fc, b_fc, out);
}

// Round 2
// 1022.900 us; speedup vs baseline: 4.8403x; 4.8403x over previous
//
#include <hip/hip_runtime.h>

#define T_LEN 512
#define HID 50
#define NBATCH 4096
#define RSTRIDE 52   // LDS row stride (staging only), columns 50/51 zeroed
#define BPW 4        // batches per wave
#define WAVES 4      // waves per block
#define CHUNK 64     // timesteps per x-prefetch chunk

__device__ __forceinline__ float rl(float v, int l) {
  return __int_as_float(__builtin_amdgcn_readlane(__float_as_int(v), l));
}
__device__ __forceinline__ float sigm(float v) { return 1.0f / (1.0f + __expf(-v)); }

__global__ __launch_bounds__(256, 1)
void gru_fused_kernel(const float* __restrict__ x,
                      const float* __restrict__ W_ih,
                      const float* __restrict__ W_hh,
                      const float* __restrict__ b_ih,
                      const float* __restrict__ b_hh,
                      const float* __restrict__ W_fc,
                      const float* __restrict__ b_fc,
                      float* __restrict__ out) {
  // ---- stage W_hh into LDS once (coalesced), zero-pad cols 50/51 ----
  __shared__ float sW[150 * RSTRIDE];
  const int tid = threadIdx.x;
  for (int i = tid; i < 150 * RSTRIDE; i += 256) sW[i] = 0.0f;
  __syncthreads();
  for (int i = tid; i < 150 * HID; i += 256) {
    int g = i / HID;
    int j = i - g * HID;
    sW[g * RSTRIDE + j] = W_hh[i];
  }
  __syncthreads();

  const int lane = tid & 63;
  const int wv   = tid >> 6;
  const int b0   = (blockIdx.x * WAVES + wv) * BPW;   // 4 consecutive batches
  const int ic   = (lane < HID) ? lane : (HID - 1);   // lanes 50-63 mirror unit 49

  // ---- per-lane input-weight / bias constants ----
  const float u_r0 = W_ih[ic * 3 + 0],         u_r1 = W_ih[ic * 3 + 1],         u_r2 = W_ih[ic * 3 + 2];
  const float u_z0 = W_ih[(50 + ic) * 3 + 0],  u_z1 = W_ih[(50 + ic) * 3 + 1],  u_z2 = W_ih[(50 + ic) * 3 + 2];
  const float u_n0 = W_ih[(100 + ic) * 3 + 0], u_n1 = W_ih[(100 + ic) * 3 + 1], u_n2 = W_ih[(100 + ic) * 3 + 2];
  const float c_r  = b_ih[ic] + b_hh[ic];
  const float c_z  = b_ih[50 + ic] + b_hh[50 + ic];
  const float c_ni = b_ih[100 + ic];
  const float c_nh = b_hh[100 + ic];

  // ---- pull this lane's full W_hh rows into REGISTERS (39 float4 = 156 VGPR) ----
  float4 wr[13], wz[13], wn[13];
  {
    const float4* Wr4 = (const float4*)(sW + ic * RSTRIDE);
    const float4* Wz4 = (const float4*)(sW + (50 + ic) * RSTRIDE);
    const float4* Wn4 = (const float4*)(sW + (100 + ic) * RSTRIDE);
#pragma unroll
    for (int q = 0; q < 13; ++q) { wr[q] = Wr4[q]; wz[q] = Wz4[q]; wn[q] = Wn4[q]; }
  }

  float h[BPW] = {0.0f, 0.0f, 0.0f, 0.0f};

  // ---- x chunk registers: lane s holds x[t0+s][0..2] for each of 4 batches ----
  float xA[BPW], xB[BPW], xC[BPW];
#pragma unroll
  for (int k = 0; k < BPW; ++k) {
    const float* p = x + (size_t)(b0 + k) * (T_LEN * 3) + lane * 3;
    xA[k] = p[0]; xB[k] = p[1]; xC[k] = p[2];
  }

  for (int tc = 0; tc < T_LEN / CHUNK; ++tc) {
    float nA[BPW], nB[BPW], nC[BPW];
    if (tc + 1 < T_LEN / CHUNK) {
#pragma unroll
      for (int k = 0; k < BPW; ++k) {
        const float* p = x + (size_t)(b0 + k) * (T_LEN * 3) + (tc + 1) * (CHUNK * 3) + lane * 3;
        nA[k] = p[0]; nB[k] = p[1]; nC[k] = p[2];
      }
    }

    for (int s = 0; s < CHUNK; ++s) {
      float ar[BPW] = {0.f, 0.f, 0.f, 0.f};
      float az[BPW] = {0.f, 0.f, 0.f, 0.f};
      float an[BPW] = {0.f, 0.f, 0.f, 0.f};

#pragma unroll
      for (int q = 0; q < 13; ++q) {
#pragma unroll
        for (int k = 0; k < BPW; ++k) {
          const float h0 = rl(h[k], 4 * q + 0);
          const float h1 = rl(h[k], 4 * q + 1);
          const float h2 = rl(h[k], 4 * q + 2);
          const float h3 = rl(h[k], 4 * q + 3);
          ar[k] = fmaf(wr[q].x, h0, ar[k]); ar[k] = fmaf(wr[q].y, h1, ar[k]);
          ar[k] = fmaf(wr[q].z, h2, ar[k]); ar[k] = fmaf(wr[q].w, h3, ar[k]);
          az[k] = fmaf(wz[q].x, h0, az[k]); az[k] = fmaf(wz[q].y, h1, az[k]);
          az[k] = fmaf(wz[q].z, h2, az[k]); az[k] = fmaf(wz[q].w, h3, az[k]);
          an[k] = fmaf(wn[q].x, h0, an[k]); an[k] = fmaf(wn[q].y, h1, an[k]);
          an[k] = fmaf(wn[q].z, h2, an[k]); an[k] = fmaf(wn[q].w, h3, an[k]);
        }
      }

#pragma unroll
      for (int k = 0; k < BPW; ++k) {
        const float x0 = rl(xA[k], s);
        const float x1 = rl(xB[k], s);
        const float x2 = rl(xC[k], s);
        const float gr = fmaf(x0, u_r0, fmaf(x1, u_r1, fmaf(x2, u_r2, c_r)));
        const float gz = fmaf(x0, u_z0, fmaf(x1, u_z1, fmaf(x2, u_z2, c_z)));
        const float gn = fmaf(x0, u_n0, fmaf(x1, u_n1, fmaf(x2, u_n2, c_ni)));
        const float r  = sigm(ar[k] + gr);
        const float z  = sigm(az[k] + gz);
        const float nv = gn + r * (an[k] + c_nh);
        const float n  = 2.0f / (1.0f + __expf(-2.0f * nv)) - 1.0f;   // tanh
        h[k] = n + z * (h[k] - n);
      }
    }

#pragma unroll
    for (int k = 0; k < BPW; ++k) { xA[k] = nA[k]; xB[k] = nB[k]; xC[k] = nC[k]; }
  }

  // ---- FC epilogue: out[b] = b_fc + sum_i h_i * W_fc[i] ----
  const float wfc = (lane < HID) ? W_fc[lane] : 0.0f;
#pragma unroll
  for (int k = 0; k < BPW; ++k) {
    float p = (lane < HID) ? h[k] * wfc : 0.0f;
#pragma unroll
    for (int off = 32; off > 0; off >>= 1) p += __shfl_down(p, off);
    if (lane == 0) out[b0 + k] = p + b_fc[0];
  }
}

extern "C" void kernel_launch(void* const* d_in, const int* in_sizes, int n_in,
                              void* d_out, int out_size, void* d_ws, size_t ws_size,
                              hipStream_t stream) {
  const float* x    = (const float*)d_in[0];
  const float* W_ih = (const float*)d_in[1];
  const float* W_hh = (const float*)d_in[2];
  const float* b_ih = (const float*)d_in[3];
  const float* b_hh = (const float*)d_in[4];
  const float* W_fc = (const float*)d_in[5];
  const float* b_fc = (const float*)d_in[6];
  float* out = (float*)d_out;

  dim3 grid(NBATCH / (WAVES * BPW));   // 256 blocks, 1 per CU
  dim3 block(256);                     // 4 waves
  gru_fused_kernel<<<grid, block, 0, stream>>>(x, W_ih, W_hh, b_ih, b_hh, W_fc, b_fc, out);
}

// Round 3
// 889.936 us; speedup vs baseline: 5.5635x; 1.1494x over previous
//
#include <hip/hip_runtime.h>

#define T_LEN 512
#define HID 50
#define NBATCH 4096
#define RSTRIDE 52   // LDS row stride, cols 50/51 zeroed
#define BPW 2        // batches per wave
#define WAVES 4      // waves per block
#define CHUNK 64     // timesteps per x-prefetch chunk

__device__ __forceinline__ float rl(float v, int l) {
  return __int_as_float(__builtin_amdgcn_readlane(__float_as_int(v), l));
}
// native sigmoid / tanh via v_exp_f32 (2^x) + v_rcp_f32
__device__ __forceinline__ float sigm(float v) {
  return __builtin_amdgcn_rcpf(1.0f + __builtin_amdgcn_exp2f(-1.442695041f * v));
}
__device__ __forceinline__ float tanh_f(float v) {
  return 1.0f - 2.0f * __builtin_amdgcn_rcpf(1.0f + __builtin_amdgcn_exp2f(2.885390082f * v));
}

__global__ __launch_bounds__(256, 2)
void gru_fused_kernel(const float* __restrict__ x,
                      const float* __restrict__ W_ih,
                      const float* __restrict__ W_hh,
                      const float* __restrict__ b_ih,
                      const float* __restrict__ b_hh,
                      const float* __restrict__ W_fc,
                      const float* __restrict__ b_fc,
                      float* __restrict__ out) {
  __shared__ float sW[150 * RSTRIDE];
  const int tid = threadIdx.x;
  for (int i = tid; i < 150 * RSTRIDE; i += 256) sW[i] = 0.0f;
  __syncthreads();
  for (int i = tid; i < 150 * HID; i += 256) {
    int g = i / HID;
    int j = i - g * HID;
    sW[g * RSTRIDE + j] = W_hh[i];
  }
  __syncthreads();

  const int lane = tid & 63;
  const int wv   = tid >> 6;
  const int b0   = (blockIdx.x * WAVES + wv) * BPW;
  const int ic   = (lane < HID) ? lane : (HID - 1);

  const float u_r0 = W_ih[ic * 3 + 0],         u_r1 = W_ih[ic * 3 + 1],         u_r2 = W_ih[ic * 3 + 2];
  const float u_z0 = W_ih[(50 + ic) * 3 + 0],  u_z1 = W_ih[(50 + ic) * 3 + 1],  u_z2 = W_ih[(50 + ic) * 3 + 2];
  const float u_n0 = W_ih[(100 + ic) * 3 + 0], u_n1 = W_ih[(100 + ic) * 3 + 1], u_n2 = W_ih[(100 + ic) * 3 + 2];
  const float c_r  = b_ih[ic] + b_hh[ic];
  const float c_z  = b_ih[50 + ic] + b_hh[50 + ic];
  const float c_ni = b_ih[100 + ic];
  const float c_nh = b_hh[100 + ic];

  // lane's W_hh rows as register arrays (fits under the 256-VGPR cap at 2 waves/EU)
  float4 wr[13], wz[13], wn[13];
  {
    const float4* Wr4 = (const float4*)(sW + ic * RSTRIDE);
    const float4* Wz4 = (const float4*)(sW + (50 + ic) * RSTRIDE);
    const float4* Wn4 = (const float4*)(sW + (100 + ic) * RSTRIDE);
#pragma unroll
    for (int q = 0; q < 13; ++q) { wr[q] = Wr4[q]; wz[q] = Wz4[q]; wn[q] = Wn4[q]; }
  }

  float h[BPW] = {0.0f, 0.0f};

  float xA[BPW], xB[BPW], xC[BPW];
#pragma unroll
  for (int k = 0; k < BPW; ++k) {
    const float* p = x + (size_t)(b0 + k) * (T_LEN * 3) + lane * 3;
    xA[k] = p[0]; xB[k] = p[1]; xC[k] = p[2];
  }

  for (int tc = 0; tc < T_LEN / CHUNK; ++tc) {
    float nA[BPW], nB[BPW], nC[BPW];
    if (tc + 1 < T_LEN / CHUNK) {
#pragma unroll
      for (int k = 0; k < BPW; ++k) {
        const float* p = x + (size_t)(b0 + k) * (T_LEN * 3) + (tc + 1) * (CHUNK * 3) + lane * 3;
        nA[k] = p[0]; nB[k] = p[1]; nC[k] = p[2];
      }
    }

    for (int s = 0; s < CHUNK; ++s) {
      float ar[BPW] = {0.f, 0.f};
      float az[BPW] = {0.f, 0.f};
      float an[BPW] = {0.f, 0.f};

#pragma unroll
      for (int q = 0; q < 13; ++q) {
#pragma unroll
        for (int k = 0; k < BPW; ++k) {
          const float h0 = rl(h[k], 4 * q + 0);
          const float h1 = rl(h[k], 4 * q + 1);
          const float h2 = rl(h[k], 4 * q + 2);
          const float h3 = rl(h[k], 4 * q + 3);
          ar[k] = fmaf(wr[q].x, h0, ar[k]); ar[k] = fmaf(wr[q].y, h1, ar[k]);
          ar[k] = fmaf(wr[q].z, h2, ar[k]); ar[k] = fmaf(wr[q].w, h3, ar[k]);
          az[k] = fmaf(wz[q].x, h0, az[k]); az[k] = fmaf(wz[q].y, h1, az[k]);
          az[k] = fmaf(wz[q].z, h2, az[k]); az[k] = fmaf(wz[q].w, h3, az[k]);
          an[k] = fmaf(wn[q].x, h0, an[k]); an[k] = fmaf(wn[q].y, h1, an[k]);
          an[k] = fmaf(wn[q].z, h2, an[k]); an[k] = fmaf(wn[q].w, h3, an[k]);
        }
      }

#pragma unroll
      for (int k = 0; k < BPW; ++k) {
        const float x0 = rl(xA[k], s);
        const float x1 = rl(xB[k], s);
        const float x2 = rl(xC[k], s);
        const float gr = fmaf(x0, u_r0, fmaf(x1, u_r1, fmaf(x2, u_r2, c_r)));
        const float gz = fmaf(x0, u_z0, fmaf(x1, u_z1, fmaf(x2, u_z2, c_z)));
        const float gn = fmaf(x0, u_n0, fmaf(x1, u_n1, fmaf(x2, u_n2, c_ni)));
        const float r  = sigm(ar[k] + gr);
        const float z  = sigm(az[k] + gz);
        const float nv = gn + r * (an[k] + c_nh);
        const float n  = tanh_f(nv);
        h[k] = n + z * (h[k] - n);
      }
    }

#pragma unroll
    for (int k = 0; k < BPW; ++k) { xA[k] = nA[k]; xB[k] = nB[k]; xC[k] = nC[k]; }
  }

  const float wfc = (lane < HID) ? W_fc[lane] : 0.0f;
#pragma unroll
  for (int k = 0; k < BPW; ++k) {
    float p = (lane < HID) ? h[k] * wfc : 0.0f;
#pragma unroll
    for (int off = 32; off > 0; off >>= 1) p += __shfl_down(p, off);
    if (lane == 0) out[b0 + k] = p + b_fc[0];
  }
}

extern "C" void kernel_launch(void* const* d_in, const int* in_sizes, int n_in,
                              void* d_out, int out_size, void* d_ws, size_t ws_size,
                              hipStream_t stream) {
  const float* x    = (const float*)d_in[0];
  const float* W_ih = (const float*)d_in[1];
  const float* W_hh = (const float*)d_in[2];
  const float* b_ih = (const float*)d_in[3];
  const float* b_hh = (const float*)d_in[4];
  const float* W_fc = (const float*)d_in[5];
  const float* b_fc = (const float*)d_in[6];
  float* out = (float*)d_out;

  dim3 grid(NBATCH / (WAVES * BPW));   // 512 blocks -> 2 blocks/CU -> 2 waves/SIMD
  dim3 block(256);
  gru_fused_kernel<<<grid, block, 0, stream>>>(x, W_ih, W_hh, b_ih, b_hh, W_fc, b_fc, out);
}